// Round 3
// baseline (63.860 us; speedup 1.0000x reference)
//
#include <hip/hip_runtime.h>
#include <math.h>

// CoverageLoss:
//   N=32 images, Bp=8 boxes/img, F=16 fragments, FP=64 points/fragment.
//   Boundary samples: 100 pts = { (0,t),(1,t),(t,0),(t,1) : t=j/24, j=0..24 }.
//   val(n,f,fp) = min_b [ inside_b ? 0 : min_s ||frag - sample(b,s)||^2 ]
//   out = sum val / 2048.
//
// SINGLE dispatch: 512 worker blocks (1 wave each) + 1 reducer block.
//   Workers: closed-form nearest-boundary-sample (j* = rint(24u), eval j*-1..j*+1
//   per axis -- parabola min over uniform samples is at the nearest sample;
//   +/-1 window absorbs ulp-level f32 argmin flips).
//   Publish: partial (relaxed, agent scope) then MAGIC flag (release, agent
//   scope -- device scope is required for cross-XCD visibility).
//   Reducer (block 512): acquire-spin on 512 flags, sum, write d_out.
//   Init-free: flags are 0xAAAAAAAA poison (!= MAGIC) before every timed
//   replay; even a stale MAGIC is benign since partials are deterministic.

#define NIMG 32
#define BPB  8
#define NF   16
#define NFP  64
#define NWORK (NIMG * NF)          // 512
#define MAGIC 0x5CA1AB1Eu

__global__ __launch_bounds__(64) void coverage_fused_kernel(
    const float* __restrict__ boxes,     // (256, 4) xc,yc,w,h
    const float* __restrict__ frags,     // (32,16,64,2)
    float* __restrict__ partials,        // ws[0..511]
    unsigned int* __restrict__ flags,    // ws[512..1023]
    float* __restrict__ out)             // scalar
{
    const int blk  = blockIdx.x;
    const int lane = threadIdx.x;

    if (blk < NWORK) {
        // ---------------- worker: one wave, one (n,f), lane = point ----------
        const int n = blk >> 4;
        const float2 fr = reinterpret_cast<const float2*>(frags)[blk * NFP + lane];
        const float fx = fr.x, fy = fr.y;
        const float inv24 = 1.0f / 24.0f;

        float val = INFINITY;
        const float* bptr = boxes + n * BPB * 4;   // wave-uniform -> scalar loads
        #pragma unroll
        for (int b = 0; b < BPB; ++b) {
            const float xc = bptr[b * 4 + 0];
            const float yc = bptr[b * 4 + 1];
            const float w  = bptr[b * 4 + 2];
            const float h  = bptr[b * 4 + 3];
            const float lx = xc - 0.5f * w;
            const float ly = yc - 0.5f * h;
            const float hx = xc + 0.5f * w;
            const float hy = yc + 0.5f * h;
            const float ww = hx - lx;              // reference: wh = hi - lo
            const float hh = hy - ly;

            const float dx0 = fx - lx;             // t=0 edge offsets
            const float dy0 = fy - ly;
            const float dx1 = fx - (lx + ww);      // t=1 edge (fma(1,ww,lx)=lx+ww)
            const float dy1 = fy - (ly + hh);

            const bool inside = (dx0 >= 0.0f) && (dy0 >= 0.0f) &&
                                (hx - fx >= 0.0f) && (hy - fy >= 0.0f);

            const float dx0s = dx0 * dx0, dx1s = dx1 * dx1;
            const float dy0s = dy0 * dy0, dy1s = dy1 * dy1;

            // nearest sample index along each axis (approx rcp is fine: only
            // steers index selection; +/-1 window covers any rounding skew)
            const float jxf = rintf(dx0 * __builtin_amdgcn_rcpf(ww) * 24.0f);
            const float jyf = rintf(dy0 * __builtin_amdgcn_rcpf(hh) * 24.0f);

            float exs = INFINITY, eys = INFINITY;
            #pragma unroll
            for (int d = -1; d <= 1; ++d) {
                const float jx = fminf(fmaxf(jxf + (float)d, 0.0f), 24.0f);
                const float jy = fminf(fmaxf(jyf + (float)d, 0.0f), 24.0f);
                const float tx = jx * inv24;       // == j*(1/24f), matches ref grid
                const float ty = jy * inv24;
                const float ex = fx - fmaf(tx, ww, lx);
                const float ey = fy - fmaf(ty, hh, ly);
                exs = fminf(exs, ex * ex);
                eys = fminf(eys, ey * ey);
            }
            // min over 4 edges; min(a,b)+c == min(a+c,b+c) exactly (rounding
            // is monotone), matching the reference's per-sample adds
            const float m = fminf(fminf(dx0s, dx1s) + eys,
                                  exs + fminf(dy0s, dy1s));
            val = fminf(val, inside ? 0.0f : m);
        }

        // wave-64 shuffle reduction
        float s = val;
        #pragma unroll
        for (int off = 32; off > 0; off >>= 1)
            s += __shfl_down(s, off, 64);

        if (lane == 0) {
            __hip_atomic_store(&partials[blk], s,
                               __ATOMIC_RELAXED, __HIP_MEMORY_SCOPE_AGENT);
            __hip_atomic_store(&flags[blk], MAGIC,
                               __ATOMIC_RELEASE, __HIP_MEMORY_SCOPE_AGENT);
        }
    } else {
        // ---------------- reducer: 1 wave, 8 flags+partials per lane ---------
        float s = 0.0f;
        #pragma unroll
        for (int k = 0; k < NWORK / 64; ++k) {
            const int i = lane + 64 * k;
            while (__hip_atomic_load(&flags[i], __ATOMIC_ACQUIRE,
                                     __HIP_MEMORY_SCOPE_AGENT) != MAGIC)
                __builtin_amdgcn_s_sleep(2);
            s += __hip_atomic_load(&partials[i], __ATOMIC_RELAXED,
                                   __HIP_MEMORY_SCOPE_AGENT);
        }
        #pragma unroll
        for (int off = 32; off > 0; off >>= 1)
            s += __shfl_down(s, off, 64);
        if (lane == 0)
            out[0] = s * (1.0f / 2048.0f);
    }
}

extern "C" void kernel_launch(void* const* d_in, const int* in_sizes, int n_in,
                              void* d_out, int out_size, void* d_ws, size_t ws_size,
                              hipStream_t stream) {
    const float* boxes = (const float*)d_in[0];   // (256, 4) f32
    const float* frags = (const float*)d_in[1];   // (32,16,64,2) f32
    // d_in[2] = obj_to_img (unused by the reference computation)
    float*        partials = (float*)d_ws;
    unsigned int* flags    = (unsigned int*)d_ws + NWORK;
    float*        out      = (float*)d_out;

    coverage_fused_kernel<<<NWORK + 1, 64, 0, stream>>>(boxes, frags,
                                                        partials, flags, out);
}

// Round 4
// 60.091 us; speedup vs baseline: 1.0627x; 1.0627x over previous
//
#include <hip/hip_runtime.h>
#include <math.h>

// CoverageLoss:
//   N=32 images, Bp=8 boxes/img, F=16 fragments, FP=64 points/fragment.
//   Boundary samples: 100 pts = { (0,t),(1,t),(t,0),(t,1) : t=j/24, j=0..24 }.
//   val(n,f,fp) = min_b [ inside_b ? 0 : min_s ||frag - sample(b,s)||^2 ]
//   out = sum val / 2048.
//
// Two dispatches (measured faster than fused-spin variant):
//   k1: 512 blocks (1 wave each), closed-form nearest-sample math,
//       partial sums -> d_ws (pure overwrite, no init needed)
//   k2: 1 wave reduces 512 partials -> d_out[0]
//
// Closed-form: min over uniform samples t=j/24 of the per-axis parabola is
// attained at the sample nearest the vertex; evaluate j*-1..j*+1 (clamped)
// to absorb ulp-level argmin flips. Verified absmax == 0.0 vs jax ref (R3).

#define NIMG 32
#define BPB  8
#define NF   16
#define NFP  64
#define NBLK (NIMG * NF)   // 512

__global__ __launch_bounds__(64) void coverage_partial_kernel(
    const float* __restrict__ boxes,    // (256, 4) xc,yc,w,h
    const float* __restrict__ frags,    // (32,16,64,2)
    float* __restrict__ partials)       // (NBLK,) in d_ws, overwritten
{
    const int blk  = blockIdx.x;        // n*NF + f
    const int n    = blk >> 4;
    const int lane = threadIdx.x;       // fp index, one wave per block

    const float2 fr = reinterpret_cast<const float2*>(frags)[blk * NFP + lane];
    const float fx = fr.x, fy = fr.y;
    const float inv24 = 1.0f / 24.0f;

    float val = INFINITY;
    const float* bptr = boxes + n * BPB * 4;   // wave-uniform -> scalar loads
    #pragma unroll
    for (int b = 0; b < BPB; ++b) {
        const float xc = bptr[b * 4 + 0];
        const float yc = bptr[b * 4 + 1];
        const float w  = bptr[b * 4 + 2];
        const float h  = bptr[b * 4 + 3];
        const float lx = xc - 0.5f * w;
        const float ly = yc - 0.5f * h;
        const float hx = xc + 0.5f * w;
        const float hy = yc + 0.5f * h;
        const float ww = hx - lx;              // reference: wh = hi - lo
        const float hh = hy - ly;

        const float dx0 = fx - lx;             // t=0 edge offsets
        const float dy0 = fy - ly;
        const float dx1 = fx - (lx + ww);      // t=1 edge (fma(1,ww,lx)=lx+ww)
        const float dy1 = fy - (ly + hh);

        const bool inside = (dx0 >= 0.0f) && (dy0 >= 0.0f) &&
                            (hx - fx >= 0.0f) && (hy - fy >= 0.0f);

        const float dx0s = dx0 * dx0, dx1s = dx1 * dx1;
        const float dy0s = dy0 * dy0, dy1s = dy1 * dy1;

        // nearest sample index along each axis (approx rcp only steers index
        // selection; the +/-1 window covers any rounding skew)
        const float jxf = rintf(dx0 * __builtin_amdgcn_rcpf(ww) * 24.0f);
        const float jyf = rintf(dy0 * __builtin_amdgcn_rcpf(hh) * 24.0f);

        float exs = INFINITY, eys = INFINITY;
        #pragma unroll
        for (int d = -1; d <= 1; ++d) {
            const float jx = fminf(fmaxf(jxf + (float)d, 0.0f), 24.0f);
            const float jy = fminf(fmaxf(jyf + (float)d, 0.0f), 24.0f);
            const float tx = jx * inv24;       // == j*(1/24f), matches ref grid
            const float ty = jy * inv24;
            const float ex = fx - fmaf(tx, ww, lx);
            const float ey = fy - fmaf(ty, hh, ly);
            exs = fminf(exs, ex * ex);
            eys = fminf(eys, ey * ey);
        }
        // min over 4 edges; min(a,b)+c == min(a+c,b+c) exactly (monotone
        // rounding), matching the reference's per-sample adds
        const float m = fminf(fminf(dx0s, dx1s) + eys,
                              exs + fminf(dy0s, dy1s));
        val = fminf(val, inside ? 0.0f : m);
    }

    // wave-64 shuffle reduction
    float s = val;
    #pragma unroll
    for (int off = 32; off > 0; off >>= 1)
        s += __shfl_down(s, off, 64);

    if (lane == 0)
        partials[blk] = s;
}

__global__ __launch_bounds__(64) void coverage_reduce_kernel(
    const float* __restrict__ partials,  // (NBLK,)
    float* __restrict__ out)             // scalar, overwritten
{
    const int lane = threadIdx.x;
    float s = 0.0f;
    #pragma unroll
    for (int k = 0; k < NBLK / 64; ++k)
        s += partials[lane + 64 * k];
    #pragma unroll
    for (int off = 32; off > 0; off >>= 1)
        s += __shfl_down(s, off, 64);
    if (lane == 0)
        out[0] = s * (1.0f / 2048.0f);
}

extern "C" void kernel_launch(void* const* d_in, const int* in_sizes, int n_in,
                              void* d_out, int out_size, void* d_ws, size_t ws_size,
                              hipStream_t stream) {
    const float* boxes = (const float*)d_in[0];   // (256, 4) f32
    const float* frags = (const float*)d_in[1];   // (32,16,64,2) f32
    // d_in[2] = obj_to_img (unused by the reference computation)
    float* partials = (float*)d_ws;
    float* out = (float*)d_out;

    coverage_partial_kernel<<<NBLK, 64, 0, stream>>>(boxes, frags, partials);
    coverage_reduce_kernel<<<1, 64, 0, stream>>>(partials, out);
}